// Round 1
// 357.291 us; speedup vs baseline: 1.0694x; 1.0694x over previous
//
#include <hip/hip_runtime.h>

// Problem constants (fixed by the reference)
#define NN 8192
#define NE 262144
#define NB_AGG 128            // partial-aggregation blocks
#define EPB (NE / NB_AGG)     // 2048 edges per block

__device__ __forceinline__ float bf2f(unsigned short h) {
    return __uint_as_float(((unsigned int)h) << 16);
}

// Runtime float-dtype hedge: bf16-packed data has EVERY 16-bit half looking
// like a bf16 float of moderate exponent; genuine fp32 data has uniform
// mantissa bits in the low halves. Check low-half exponent field of 16 words.
__device__ __forceinline__ int detect_bf16(const void* p) {
    const unsigned int* w = (const unsigned int*)p;
    int all = 1;
    for (int i = 0; i < 16; ++i) {
        unsigned int el = (w[i] >> 7) & 0xFFu;  // low-half exponent field
        all &= (el >= 64u && el < 160u) ? 1 : 0;
    }
    return all;
}
__device__ __forceinline__ float loadf(const void* p, size_t i, int isbf) {
    return isbf ? bf2f(((const unsigned short*)p)[i]) : ((const float*)p)[i];
}

// ---------------------------------------------------------------------------
// Kernel 1: LDS-privatized segment_sum of edge_attr by source node.
// Each of NB_AGG blocks owns a private [4][NN] fp32 table in LDS (128 KB,
// SoA so random node ids hit all 32 banks), accumulates its EPB edges with
// LDS atomics (contention-free in practice: 2048 edges over 8192 nodes),
// then flushes the dense table to global partials[block]. ZERO global atomics.
// edge_index hedge: little-endian int64 values < 8192 have zero odd words.
// ---------------------------------------------------------------------------
__global__ __launch_bounds__(256) void k_edge_agg_part(
    const int* edge_index, const void* edge_attr, float* partials)
{
    __shared__ float tbl[4 * NN];   // 131072 B — fits gfx950's 160 KB LDS
    const int t = threadIdx.x;
    {   // zero the table (vectorized: 8192 float4 stores / 256 threads)
        float4* t4 = (float4*)tbl;
        const float4 z = make_float4(0.f, 0.f, 0.f, 0.f);
        for (int i = t; i < NN; i += 256) t4[i] = z;
    }
    __syncthreads();

    const bool is64 =
        (edge_index[1] | edge_index[3] | edge_index[5] | edge_index[7] |
         edge_index[9] | edge_index[11] | edge_index[13] | edge_index[15]) == 0;
    const int isbf = detect_bf16(edge_attr);

    const int e0 = blockIdx.x * EPB;
    for (int k = 0; k < EPB; k += 256) {
        const int e = e0 + k + t;
        int r;
        if (is64) r = (int)(((const long long*)edge_index)[e]);  // 8B coalesced
        else      r = edge_index[e];
        float a0, a1, a2, a3;
        if (!isbf) {
            const float4 v = ((const float4*)edge_attr)[e];      // 16B coalesced
            a0 = v.x; a1 = v.y; a2 = v.z; a3 = v.w;
        } else {
            const ushort4 v = ((const ushort4*)edge_attr)[e];
            a0 = bf2f(v.x); a1 = bf2f(v.y); a2 = bf2f(v.z); a3 = bf2f(v.w);
        }
        atomicAdd(&tbl[0 * NN + r], a0);   // ds_add_f32, SoA: bank = r % 32
        atomicAdd(&tbl[1 * NN + r], a1);
        atomicAdd(&tbl[2 * NN + r], a2);
        atomicAdd(&tbl[3 * NN + r], a3);
    }
    __syncthreads();

    // dense coalesced flush: 8192 float4s / 256 threads = 32 per thread
    float4* dst = (float4*)(partials + (size_t)blockIdx.x * 4 * NN);
    const float4* src = (const float4*)tbl;
    for (int i = t; i < NN; i += 256) dst[i] = src[i];
}

// ---------------------------------------------------------------------------
// Kernel 2: fold the NB_AGG partials (coalesced: thread n reads element n of
// each [c][NN] plane) + node MLP chain (15->4->4->2) in fp32, 1 thread/node.
// Writes fp32 emb to the output-1 region (d_out + NN*NN fp32 elements).
// ---------------------------------------------------------------------------
__global__ __launch_bounds__(256) void k_node_mlp(
    const float* partials, const void* node_feats,
    const void* W1, const void* b1, const void* W2, const void* b2,
    const void* We, const void* be,
    float* emb)                 // fp32 [NN,2] at d_out tail
{
    const int n = blockIdx.x * 256 + threadIdx.x;
    if (n >= NN) return;
    const int isbf = detect_bf16(node_feats);  // same policy for all floats

    float in[15];
    for (int k = 0; k < 11; ++k) in[k] = loadf(node_feats, (size_t)n * 11 + k, isbf);

    float a0 = 0.f, a1 = 0.f, a2 = 0.f, a3 = 0.f;
    for (int b = 0; b < NB_AGG; ++b) {
        const float* p = partials + (size_t)b * 4 * NN;
        a0 += p[0 * NN + n];
        a1 += p[1 * NN + n];
        a2 += p[2 * NN + n];
        a3 += p[3 * NN + n];
    }
    in[11] = a0; in[12] = a1; in[13] = a2; in[14] = a3;

    float h[4];
    for (int j = 0; j < 4; ++j) {
        float acc = loadf(b1, j, isbf);
        for (int k = 0; k < 15; ++k) acc += in[k] * loadf(W1, k * 4 + j, isbf);
        h[j] = acc;
    }
    float o[4];
    for (int j = 0; j < 4; ++j) {
        float acc = loadf(b2, j, isbf);
        for (int k = 0; k < 4; ++k) acc += h[k] * loadf(W2, k * 4 + j, isbf);
        o[j] = acc;
    }
    float e0 = loadf(be, 0, isbf), e1 = loadf(be, 1, isbf);
    for (int k = 0; k < 4; ++k) {
        e0 += o[k] * loadf(We, k * 2 + 0, isbf);
        e1 += o[k] * loadf(We, k * 2 + 1, isbf);
    }
    emb[(size_t)n * 2 + 0] = e0;
    emb[(size_t)n * 2 + 1] = e1;
}

// ---------------------------------------------------------------------------
// Kernel 3: decode — adj[i][j] = sigmoid(10*||emb_i - emb_j||^2 - 1), diag 0.
// fp32 output. 256 threads x 4 consecutive cols (float4 store), 64 rows/block.
// Grid = 8 col-blocks x 128 row-blocks = 1024 blocks; coverage trivially total.
// ---------------------------------------------------------------------------
__global__ __launch_bounds__(256) void k_decode(
    const float* emb, float* adj)
{
    __shared__ float xi[64], yi[64];
    const int cb = blockIdx.x & 7;       // 8 col blocks of 1024
    const int rb = blockIdx.x >> 3;      // 128 row blocks of 64
    const int r0 = rb * 64;
    const int t  = threadIdx.x;
    const int jbase = cb * 1024 + t * 4;

    float xj[4], yj[4];
    for (int k = 0; k < 4; ++k) {
        xj[k] = emb[(size_t)(jbase + k) * 2 + 0];
        yj[k] = emb[(size_t)(jbase + k) * 2 + 1];
    }
    if (t < 64) {
        xi[t] = emb[(size_t)(r0 + t) * 2 + 0];
        yi[t] = emb[(size_t)(r0 + t) * 2 + 1];
    }
    __syncthreads();

    const float C1  = 1.4426950408889634f;   // log2(e)
    const float C10 = 14.426950408889634f;   // 10*log2(e)

    for (int r = 0; r < 64; ++r) {
        const int row = r0 + r;
        const float x = xi[r], y = yi[r];
        float4 v;
        float s[4];
        for (int k = 0; k < 4; ++k) {
            float dx = x - xj[k];
            float dy = y - yj[k];
            float d  = fmaf(dx, dx, dy * dy);
            // sigmoid(10d-1) = 1 / (1 + exp(1-10d)); exp via exp2
            float ex = exp2f(C1 - C10 * d);
            float sv = 1.0f / (1.0f + ex);
            if (jbase + k == row) sv = 0.0f;
            s[k] = sv;
        }
        v.x = s[0]; v.y = s[1]; v.z = s[2]; v.w = s[3];
        *(float4*)(adj + (size_t)row * NN + jbase) = v;
    }
}

// ---------------------------------------------------------------------------
extern "C" void kernel_launch(void* const* d_in, const int* in_sizes, int n_in,
                              void* d_out, int out_size, void* d_ws, size_t ws_size,
                              hipStream_t stream)
{
    const void* node_feats = d_in[0];
    const int*  edge_index = (const int*)d_in[1];
    const void* edge_attr  = d_in[2];
    const void* W1 = d_in[3];
    const void* b1 = d_in[4];
    const void* W2 = d_in[5];
    const void* b2 = d_in[6];
    const void* We = d_in[7];
    const void* be = d_in[8];

    float* adj = (float*)d_out;                     // fp32 [NN*NN]
    float* emb = adj + (size_t)NN * NN;             // fp32 [NN,2] (output 1)
    // partials [NB_AGG][4][NN] fp32 = 16 MB, carved from the head of the adj
    // region; fully written by k_edge_agg_part (no memset needed), consumed
    // by k_node_mlp, then overwritten by k_decode.
    float* partials = adj;

    hipLaunchKernelGGL(k_edge_agg_part, dim3(NB_AGG), dim3(256), 0, stream,
                       edge_index, edge_attr, partials);
    hipLaunchKernelGGL(k_node_mlp, dim3(NN / 256), dim3(256), 0, stream,
                       partials, node_feats, W1, b1, W2, b2, We, be, emb);
    hipLaunchKernelGGL(k_decode, dim3(1024), dim3(256), 0, stream, emb, adj);
}